// Round 10
// baseline (58.833 us; speedup 1.0000x reference)
//
#include <hip/hip_runtime.h>
#include <hip/hip_bf16.h>
#include <stdint.h>

typedef __attribute__((ext_vector_type(8)))  __bf16   bf16x8;
typedef __attribute__((ext_vector_type(16))) float    f32x16;
typedef __attribute__((ext_vector_type(8)))  float    f32x8;

#define NB   32
#define NN   2000
#define NK   32
#define NF   64
#define NOUT 128
#define NSTEP 130   // packed K: 2048 x-part + 32 dist, /16

#define GLOBAL_AS __attribute__((address_space(1)))
#define LDS_AS    __attribute__((address_space(3)))
#define SB() __builtin_amdgcn_sched_barrier(0)

// ---------------------------------------------------------------------------
// Fused prep (verified R6-R9). Blocks [0,NN): x -> xb2 frag-order tiles via
// LDS transpose + dist -> db bf16. Blocks [NN,NN+NSTEP): W -> Wf B-frag order.
// xb2 tile byte t*16 holds x[batch=col][f=s*16+half*8+j], t=s*64+half*32+col.
// Wf byte = kstep*4096 + wv*1024 + lane*16; o=wv*32+(lane&31), k=kstep*16+(lane>>5)*8+j.
// ---------------------------------------------------------------------------
__global__ void kprep(const float* __restrict__ x, const float* __restrict__ dist,
                      const float* __restrict__ W,
                      __bf16* __restrict__ xb2, __bf16* __restrict__ db,
                      __bf16* __restrict__ Wf) {
  const int t = threadIdx.x;
  if (blockIdx.x < NN) {
    __shared__ __bf16 sm[32 * 66];
    const int n = blockIdx.x;
    const int bb = t >> 3;
    const int f0 = (t & 7) << 3;
    const float* src = x + ((size_t)bb * NN + n) * NF + f0;
    f32x8 v = *(const f32x8*)src;
    bf16x8 r;
#pragma unroll
    for (int j = 0; j < 8; ++j) r[j] = (__bf16)v[j];
    *(bf16x8*)&sm[bb * 66 + f0] = r;
    __syncthreads();
    const int col = t & 31, half = (t >> 5) & 1, s = t >> 6;
    bf16x8 o = *(const bf16x8*)&sm[col * 66 + s * 16 + half * 8];
    *(bf16x8*)((char*)xb2 + ((size_t)n << 12) + t * 16) = o;
    if (t < NK) db[n * NK + t] = (__bf16)dist[n * NK + t];
  } else {
    const int kstep = blockIdx.x - NN;
    const int lane = t & 63;
    const int wv = t >> 6;
    const int o = wv * 32 + (lane & 31);
    const int kbase = kstep * 16 + (lane >> 5) * 8;
    bf16x8 r;
#pragma unroll
    for (int j = 0; j < 8; ++j) {
      const int kg = kbase + j;
      const int c = (kg < 2048) ? ((kg >> 6) * 65 + (kg & 63)) : ((kg - 2048) * 65 + 64);
      r[j] = (__bf16)W[(size_t)o * 2080 + c];
    }
    *(bf16x8*)(Wf + (((size_t)kstep * 256 + t) << 3)) = r;
  }
}

// ---------------------------------------------------------------------------
// Main: block = 4 n, 4 waves = (nh = w>>1) x (ogp = w&1).
// Wave computes its n-pair {na=2nh, nb=2nh+1} x og-pair: acc[2 n][2 og].
// Superchunk = 2 neighbors = 8 ksteps -> 32 MFMA/wave/period, 16 periods.
// Depth-2 LDS (2 x 8 tiles = 64KB). Per period:
//   [loadB(sc+1) | vmcnt(16) | barrier | stage(sc+1) | compute(sc)]
// queue = [L(sc):16, S(sc):8, L(sc+1):16] -> vmcnt(16) retires L(sc),S(sc).
// Wave (nh,ogp) stages tile q = 2nh+ogp (its n's covered by the nh pair).
// ---------------------------------------------------------------------------
__global__ __launch_bounds__(256, 2) void kmain(
    const int* __restrict__ nbrs, const float* __restrict__ bias,
    const __bf16* __restrict__ xb2, const __bf16* __restrict__ Wf,
    const __bf16* __restrict__ db, float* __restrict__ out) {
  __shared__ __align__(16) char lds[2][8][4096];   // [buf][q*2+p][frag tile]

  const int t    = threadIdx.x;
  const int lane = t & 63;
  const int w    = t >> 6;
  const int nh   = w >> 1;        // n-pair index
  const int ogp  = w & 1;         // out-group pair
  const int col  = lane & 31;
  const int half = lane >> 5;
  const int n0   = blockIdx.x * 4;
  const int q    = nh * 2 + ogp;  // n-local this wave stages

  f32x16 acc00 = {}, acc01 = {}, acc10 = {}, acc11 = {};   // [n(a,b)][e]

  // lane l (<32) holds neighbor l of this wave's staging n (n0+q)
  int myidx = 0;
  if (lane < NK) myidx = nbrs[(n0 + q) * NK + lane];

  // B-frag byte for (kstep, og=2*ogp+e): kstep*4096 + (2*ogp+e)*1024 + lane*16
  const char* wfb = (const char*)Wf + (ogp << 11) + lane * 16;

  auto stage = [&](int buf, int sc) {      // 2 neighbor tiles for n0+q
#pragma unroll
    for (int p = 0; p < 2; ++p) {
      const int nb = __builtin_amdgcn_readlane(myidx, sc * 2 + p);
      const char* g = (const char*)xb2 + ((size_t)nb << 12) + lane * 16;
      char* l = &lds[buf][q * 2 + p][0];
#pragma unroll
      for (int qq = 0; qq < 4; ++qq)
        __builtin_amdgcn_global_load_lds(
            (const GLOBAL_AS uint32_t*)(g + (qq << 10)),
            (LDS_AS uint32_t*)(l + (qq << 10)), 16, 0, 0);
    }
  };

  auto loadB = [&](bf16x8* B, int sc) {    // 16 frags: 8 ksteps x 2 og
    const char* base = wfb + ((size_t)sc << 15);
#pragma unroll
    for (int ps = 0; ps < 8; ++ps) {
      B[ps * 2 + 0] = *(const bf16x8*)(base + (ps << 12));
      B[ps * 2 + 1] = *(const bf16x8*)(base + (ps << 12) + 1024);
    }
  };

  auto compute = [&](int buf, const bf16x8* B) {
    __builtin_amdgcn_s_setprio(1);
#pragma unroll
    for (int p = 0; p < 2; ++p) {
#pragma unroll
      for (int s = 0; s < 4; ++s) {
        const char* la = &lds[buf][(nh * 2 + 0) * 2 + p][0] + (s << 10) + lane * 16;
        const char* lb = &lds[buf][(nh * 2 + 1) * 2 + p][0] + (s << 10) + lane * 16;
        bf16x8 a0 = *(const bf16x8*)(la);
        bf16x8 a1 = *(const bf16x8*)(lb);
        const int ps = p * 4 + s;
        acc00 = __builtin_amdgcn_mfma_f32_32x32x16_bf16(a0, B[ps * 2 + 0], acc00, 0, 0, 0);
        acc01 = __builtin_amdgcn_mfma_f32_32x32x16_bf16(a0, B[ps * 2 + 1], acc01, 0, 0, 0);
        acc10 = __builtin_amdgcn_mfma_f32_32x32x16_bf16(a1, B[ps * 2 + 0], acc10, 0, 0, 0);
        acc11 = __builtin_amdgcn_mfma_f32_32x32x16_bf16(a1, B[ps * 2 + 1], acc11, 0, 0, 0);
      }
    }
    __builtin_amdgcn_s_setprio(0);
  };

  bf16x8 BA[16], BB[16];

  // prologue: S(0), L(0)
  stage(0, 0); SB();
  loadB(BA, 0); SB();

#define PERIOD(SC, BC, BL)                                   \
  loadB(BL, (SC) + 1); SB();                                 \
  asm volatile("s_waitcnt vmcnt(16)" ::: "memory");          \
  __builtin_amdgcn_s_barrier(); SB();                        \
  stage(((SC) + 1) & 1, (SC) + 1); SB();                     \
  compute((SC) & 1, BC);

  // periods 0..13 (ping-pong BA/BB)
  for (int sc = 0; sc < 14; sc += 2) {
    PERIOD(sc + 0, BA, BB)
    PERIOD(sc + 1, BB, BA)
  }
#undef PERIOD
  // period 14: loadB(15) already in BB pattern -> issue, wait, no stage(16)
  loadB(BB, 15); SB();
  asm volatile("s_waitcnt vmcnt(16)" ::: "memory");
  __builtin_amdgcn_s_barrier(); SB();
  stage(1, 15); SB();
  compute(0, BA);
  // period 15
  asm volatile("s_waitcnt vmcnt(0)" ::: "memory");
  __builtin_amdgcn_s_barrier(); SB();
  compute(1, BB);

  // ---- distance ksteps 128,129 (A rows all equal d[n][k-slice])
#pragma unroll
  for (int s = 0; s < 2; ++s) {
    const char* wt = wfb + ((size_t)(128 + s) << 12);
    bf16x8 b0 = *(const bf16x8*)(wt);
    bf16x8 b1 = *(const bf16x8*)(wt + 1024);
    const char* dbase = (const char*)db + (size_t)(n0 + nh * 2) * 64 + s * 32 + half * 16;
    bf16x8 d0 = *(const bf16x8*)(dbase);        // n = n0 + 2nh
    bf16x8 d1 = *(const bf16x8*)(dbase + 64);   // n = n0 + 2nh + 1
    acc00 = __builtin_amdgcn_mfma_f32_32x32x16_bf16(d0, b0, acc00, 0, 0, 0);
    acc01 = __builtin_amdgcn_mfma_f32_32x32x16_bf16(d0, b1, acc01, 0, 0, 0);
    acc10 = __builtin_amdgcn_mfma_f32_32x32x16_bf16(d1, b0, acc10, 0, 0, 0);
    acc11 = __builtin_amdgcn_mfma_f32_32x32x16_bf16(d1, b1, acc11, 0, 0, 0);
  }

  // ---- epilogue: D col=lane&31 -> out col, row=(r&3)+8*(r>>2)+4*half -> batch
  const int o0 = (ogp << 6) + col;
  const int nn = n0 + nh * 2;
  const float bv0 = bias[o0], bv1 = bias[o0 + 32];
#pragma unroll
  for (int r = 0; r < 16; ++r) {
    const int row = (r & 3) + 8 * (r >> 2) + 4 * half;
    float* op = out + ((size_t)row * NN + nn) * NOUT + o0;
    op[0]         = acc00[r] + bv0;
    op[32]        = acc01[r] + bv1;
    op[NOUT]      = acc10[r] + bv0;
    op[NOUT + 32] = acc11[r] + bv1;
  }
}

// ---------------------------------------------------------------------------
extern "C" void kernel_launch(void* const* d_in, const int* in_sizes, int n_in,
                              void* d_out, int out_size, void* d_ws, size_t ws_size,
                              hipStream_t stream) {
  const float* x    = (const float*)d_in[0];
  const int*   nbrs = (const int*)d_in[1];
  const float* dist = (const float*)d_in[2];
  const float* W    = (const float*)d_in[3];
  const float* bias = (const float*)d_in[4];
  float* out = (float*)d_out;

  char* ws = (char*)d_ws;
  __bf16* xb2 = (__bf16*)(ws);                          // 2000*4096  = 8,192,000 B
  __bf16* Wf  = (__bf16*)(ws + 8192000);                // 130*256*16 =   532,480 B
  __bf16* db  = (__bf16*)(ws + 8192000 + 532480);       // 2000*32*2  =   128,000 B

  kprep<<<NN + NSTEP, 256, 0, stream>>>(x, dist, W, xb2, db, Wf);
  kmain<<<NN / 4, 256, 0, stream>>>(nbrs, bias, xb2, Wf, db, out);
}

// Round 11
// 54.926 us; speedup vs baseline: 1.0711x; 1.0711x over previous
//
#include <hip/hip_runtime.h>
#include <hip/hip_bf16.h>
#include <stdint.h>

typedef __attribute__((ext_vector_type(8)))  __bf16   bf16x8;
typedef __attribute__((ext_vector_type(16))) float    f32x16;
typedef __attribute__((ext_vector_type(8)))  float    f32x8;

#define NB   32
#define NN   2000
#define NK   32
#define NF   64
#define NOUT 128
#define NSTEP 130   // packed K: 2048 x-part + 32 dist, /16

#define GLOBAL_AS __attribute__((address_space(1)))
#define LDS_AS    __attribute__((address_space(3)))
#define SB() __builtin_amdgcn_sched_barrier(0)
#define MFMA __builtin_amdgcn_mfma_f32_32x32x16_bf16

// ---------------------------------------------------------------------------
// Fused prep (verified R6-R10). Blocks [0,NN): x -> xb2 frag-order tiles via
// LDS transpose + dist -> db bf16. Blocks [NN,NN+NSTEP): W -> Wf B-frag order.
// xb2 tile byte t*16 holds x[batch=col][f=s*16+half*8+j], t=s*64+half*32+col.
// Wf byte = kstep*4096 + wv*1024 + lane*16; o=wv*32+(lane&31), k=kstep*16+(lane>>5)*8+j.
// ---------------------------------------------------------------------------
__global__ void kprep(const float* __restrict__ x, const float* __restrict__ dist,
                      const float* __restrict__ W,
                      __bf16* __restrict__ xb2, __bf16* __restrict__ db,
                      __bf16* __restrict__ Wf) {
  const int t = threadIdx.x;
  if (blockIdx.x < NN) {
    __shared__ __bf16 sm[32 * 66];
    const int n = blockIdx.x;
    const int bb = t >> 3;
    const int f0 = (t & 7) << 3;
    const float* src = x + ((size_t)bb * NN + n) * NF + f0;
    f32x8 v = *(const f32x8*)src;
    bf16x8 r;
#pragma unroll
    for (int j = 0; j < 8; ++j) r[j] = (__bf16)v[j];
    *(bf16x8*)&sm[bb * 66 + f0] = r;
    __syncthreads();
    const int col = t & 31, half = (t >> 5) & 1, s = t >> 6;
    bf16x8 o = *(const bf16x8*)&sm[col * 66 + s * 16 + half * 8];
    *(bf16x8*)((char*)xb2 + ((size_t)n << 12) + t * 16) = o;
    if (t < NK) db[n * NK + t] = (__bf16)dist[n * NK + t];
  } else {
    const int kstep = blockIdx.x - NN;
    const int lane = t & 63;
    const int wv = t >> 6;
    const int o = wv * 32 + (lane & 31);
    const int kbase = kstep * 16 + (lane >> 5) * 8;
    bf16x8 r;
#pragma unroll
    for (int j = 0; j < 8; ++j) {
      const int kg = kbase + j;
      const int c = (kg < 2048) ? ((kg >> 6) * 65 + (kg & 63)) : ((kg - 2048) * 65 + 64);
      r[j] = (__bf16)W[(size_t)o * 2080 + c];
    }
    *(bf16x8*)(Wf + (((size_t)kstep * 256 + t) << 3)) = r;
  }
}

// ---------------------------------------------------------------------------
// Main: block = 4 n, 4 waves; wave = 1 n x ALL 128 out (acc[4 og] = 64 VGPR).
// A (random gather): direct global->register, private per wave, ping-pong one
//   period (2 neighbors = 8 frags) ahead -> gathers never gate the barrier.
// B (sequential Wf): block-cooperative global_load_lds, double-buffered 32KB
//   chunks (8 ksteps x 4 og), one barrier per period.
// Period c: [loadA(c+1) | vmcnt(8) | barrier | compute(c) | stageB(c+1)]
//   queue at wait = [A(c):8, B(c):8, A(c+1):8] -> vmcnt(8) retires A(c),B(c).
// ---------------------------------------------------------------------------
__global__ __launch_bounds__(256, 2) void kmain(
    const int* __restrict__ nbrs, const float* __restrict__ bias,
    const __bf16* __restrict__ xb2, const __bf16* __restrict__ Wf,
    const __bf16* __restrict__ db, float* __restrict__ out) {
  __shared__ __align__(16) char lds[2][32768];   // [buf][8 kstep][4 og][1KB frag]

  const int t    = threadIdx.x;
  const int lane = t & 63;
  const int w    = t >> 6;
  const int col  = lane & 31;
  const int half = lane >> 5;
  const int n0   = blockIdx.x * 4;
  const int n    = n0 + w;            // this wave's sequence position

  f32x16 acc0 = {}, acc1 = {}, acc2 = {}, acc3 = {};   // og 0..3

  int myidx = 0;
  if (lane < NK) myidx = nbrs[n * NK + lane];

  auto loadA = [&](bf16x8* A, int c) {       // 8 frags: 2 nbrs x 4 ksteps
#pragma unroll
    for (int p = 0; p < 2; ++p) {
      const int nb = __builtin_amdgcn_readlane(myidx, c * 2 + p);
      const char* g = (const char*)xb2 + ((size_t)nb << 12) + lane * 16;
#pragma unroll
      for (int s = 0; s < 4; ++s)
        A[p * 4 + s] = *(const bf16x8*)(g + (s << 10));
    }
  };

  auto stageB = [&](int c) {                 // 32KB Wf chunk -> lds[c&1], linear
    const char* g = (const char*)Wf + ((size_t)c << 15) + (w << 10) + lane * 16;
    char* l = &lds[c & 1][w << 10];
#pragma unroll
    for (int q = 0; q < 8; ++q)
      __builtin_amdgcn_global_load_lds(
          (const GLOBAL_AS uint32_t*)(g + (q << 12)),
          (LDS_AS uint32_t*)(l + (q << 12)), 16, 0, 0);
  };

  auto compute = [&](int c, const bf16x8* A) {
    const char* lb = &lds[c & 1][0] + lane * 16;
    __builtin_amdgcn_s_setprio(1);
#pragma unroll
    for (int ks = 0; ks < 8; ++ks) {
      bf16x8 b0 = *(const bf16x8*)(lb + (ks << 12));
      bf16x8 b1 = *(const bf16x8*)(lb + (ks << 12) + 1024);
      bf16x8 b2 = *(const bf16x8*)(lb + (ks << 12) + 2048);
      bf16x8 b3 = *(const bf16x8*)(lb + (ks << 12) + 3072);
      acc0 = MFMA(A[ks], b0, acc0, 0, 0, 0);
      acc1 = MFMA(A[ks], b1, acc1, 0, 0, 0);
      acc2 = MFMA(A[ks], b2, acc2, 0, 0, 0);
      acc3 = MFMA(A[ks], b3, acc3, 0, 0, 0);
    }
    __builtin_amdgcn_s_setprio(0);
  };

  bf16x8 AA[8], AB[8];

  // prologue: A(0), B(0)
  loadA(AA, 0); SB();
  stageB(0); SB();

#define BODY(C, AC, AL)                                     \
  loadA(AL, (C) + 1); SB();                                 \
  asm volatile("s_waitcnt vmcnt(8)" ::: "memory");          \
  __builtin_amdgcn_s_barrier(); SB();                       \
  compute((C), AC); SB();                                   \
  stageB((C) + 1); SB();

  // periods 0..13
  for (int c = 0; c < 14; c += 2) {
    BODY(c + 0, AA, AB)
    BODY(c + 1, AB, AA)
  }
#undef BODY
  // period 14: last loadA target unused pattern; queue [A14,B14,A15] -> vmcnt(8)
  loadA(AB, 15); SB();
  asm volatile("s_waitcnt vmcnt(8)" ::: "memory");
  __builtin_amdgcn_s_barrier(); SB();
  compute(14, AA); SB();
  stageB(15); SB();
  // period 15
  asm volatile("s_waitcnt vmcnt(0)" ::: "memory");
  __builtin_amdgcn_s_barrier(); SB();
  compute(15, AB);

  // ---- distance ksteps 128,129: A rows all equal d[n][k-slice]; B direct
#pragma unroll
  for (int s = 0; s < 2; ++s) {
    const char* wt = (const char*)Wf + ((size_t)(128 + s) << 12) + lane * 16;
    bf16x8 dv = *(const bf16x8*)((const char*)db + (size_t)n * 64 + s * 32 + half * 16);
    bf16x8 b0 = *(const bf16x8*)(wt);
    bf16x8 b1 = *(const bf16x8*)(wt + 1024);
    bf16x8 b2 = *(const bf16x8*)(wt + 2048);
    bf16x8 b3 = *(const bf16x8*)(wt + 3072);
    acc0 = MFMA(dv, b0, acc0, 0, 0, 0);
    acc1 = MFMA(dv, b1, acc1, 0, 0, 0);
    acc2 = MFMA(dv, b2, acc2, 0, 0, 0);
    acc3 = MFMA(dv, b3, acc3, 0, 0, 0);
  }

  // ---- epilogue: D col=lane&31 -> out col (og*32+col), row -> batch
  const float bv0 = bias[col], bv1 = bias[col + 32], bv2 = bias[col + 64], bv3 = bias[col + 96];
#pragma unroll
  for (int r = 0; r < 16; ++r) {
    const int row = (r & 3) + 8 * (r >> 2) + 4 * half;
    float* op = out + ((size_t)row * NN + n) * NOUT + col;
    op[0]  = acc0[r] + bv0;
    op[32] = acc1[r] + bv1;
    op[64] = acc2[r] + bv2;
    op[96] = acc3[r] + bv3;
  }
}

// ---------------------------------------------------------------------------
extern "C" void kernel_launch(void* const* d_in, const int* in_sizes, int n_in,
                              void* d_out, int out_size, void* d_ws, size_t ws_size,
                              hipStream_t stream) {
  const float* x    = (const float*)d_in[0];
  const int*   nbrs = (const int*)d_in[1];
  const float* dist = (const float*)d_in[2];
  const float* W    = (const float*)d_in[3];
  const float* bias = (const float*)d_in[4];
  float* out = (float*)d_out;

  char* ws = (char*)d_ws;
  __bf16* xb2 = (__bf16*)(ws);                          // 2000*4096  = 8,192,000 B
  __bf16* Wf  = (__bf16*)(ws + 8192000);                // 130*256*16 =   532,480 B
  __bf16* db  = (__bf16*)(ws + 8192000 + 532480);       // 2000*32*2  =   128,000 B

  kprep<<<NN + NSTEP, 256, 0, stream>>>(x, dist, W, xb2, db, Wf);
  kmain<<<NN / 4, 256, 0, stream>>>(nbrs, bias, xb2, Wf, db, out);
}

// Round 12
// 53.747 us; speedup vs baseline: 1.0946x; 1.0219x over previous
//
#include <hip/hip_runtime.h>
#include <hip/hip_bf16.h>
#include <stdint.h>

typedef __attribute__((ext_vector_type(8)))  __bf16   bf16x8;
typedef __attribute__((ext_vector_type(4)))  float    f32x4;
typedef __attribute__((ext_vector_type(8)))  float    f32x8;

#define NN   2000
#define NK   32
#define NOUT 128

#define GLOBAL_AS __attribute__((address_space(1)))
#define LDS_AS    __attribute__((address_space(3)))
#define SB() __builtin_amdgcn_sched_barrier(0)
#define MFMA16 __builtin_amdgcn_mfma_f32_16x16x32_bf16

// ---------------------------------------------------------------------------
// Prep. Blocks [0,NN): x -> xb2h[h][n] 2KB half-tiles in 16x16x32 A-frag order
//   (A lane l: row=l&15, k=(l>>4)*8+j; tile byte = ks*1024 + lane*16 + j*2,
//    element (row=b&15, f=ks*32+(l>>4)*8+j), h=b>>4)  + dist -> db bf16.
// Blocks [NN, NN+65): W -> Wf2 B-frag order: byte = kstep*8192 + og*1024 +
//   lane*16 + j*2 holds W[o=og*16+(l&15)][col(kg=kstep*32+(l>>4)*8+j)].
//   packed kg: <2048 -> col=(kg>>6)*65+(kg&63); >=2048 -> (kg-2048)*65+64.
// ---------------------------------------------------------------------------
__global__ void kprep(const float* __restrict__ x, const float* __restrict__ dist,
                      const float* __restrict__ W,
                      __bf16* __restrict__ xb2h, __bf16* __restrict__ db,
                      __bf16* __restrict__ Wf2) {
  const int t = threadIdx.x;
  if (blockIdx.x < NN) {
    const int n = blockIdx.x;
    const int b  = t >> 3;          // batch 0..31
    const int f0 = (t & 7) << 3;    // feature start 0..56
    const float* src = x + ((size_t)b * NN + n) * 64 + f0;
    f32x8 v = *(const f32x8*)src;
    bf16x8 r;
#pragma unroll
    for (int j = 0; j < 8; ++j) r[j] = (__bf16)v[j];
    const int h = b >> 4, row = b & 15;
    const int off = ((f0 >> 5) << 10) + (((((f0 >> 3) & 3) << 4) + row) << 4);
    *(bf16x8*)((char*)xb2h + ((size_t)(h * NN + n) << 11) + off) = r;
    if (t < NK) db[n * NK + t] = (__bf16)dist[n * NK + t];
  } else {
    const int kstep = blockIdx.x - NN;      // 0..64
#pragma unroll
    for (int pass = 0; pass < 2; ++pass) {
      const int it = t + pass * 256;
      const int og = it >> 6, lane = it & 63;
      const int o  = og * 16 + (lane & 15);
      const int kb = kstep * 32 + ((lane >> 4) << 3);
      bf16x8 r;
#pragma unroll
      for (int j = 0; j < 8; ++j) {
        const int kg = kb + j;
        const int col = (kg < 2048) ? ((kg >> 6) * 65 + (kg & 63)) : ((kg - 2048) * 65 + 64);
        r[j] = (__bf16)W[(size_t)o * 2080 + col];
      }
      *(bf16x8*)((char*)Wf2 + (size_t)kstep * 8192 + og * 1024 + lane * 16) = r;
    }
  }
}

// ---------------------------------------------------------------------------
// Main: block = (half h = bid&1, 8 n), 4 waves; wave = 2 n x ALL 128 out.
// h = bid&1 + round-robin dispatch -> each XCD gathers from ONE 4.1MB half
// table -> L2-resident random gathers.
// A: direct global->reg (4 loads/period), wave-private, 1-period prefetch.
// B: cooperative global_load_lds, 16KB/period dbuf, one barrier/period.
// Period c: [loadA(c+1):4 | vmcnt(4) | barrier | compute(c) | stageB(c+1):4]
//   queue at wait = [A(c):4, B(c):4, A(c+1):4] -> vmcnt(4) retires A(c),B(c).
// ---------------------------------------------------------------------------
__global__ __launch_bounds__(256, 2) void kmain(
    const int* __restrict__ nbrs, const float* __restrict__ bias,
    const __bf16* __restrict__ xb2h, const __bf16* __restrict__ Wf2,
    const __bf16* __restrict__ db, float* __restrict__ out) {
  __shared__ __align__(16) char lds[2][16384];   // [buf][2 kstep][8 og][1KB frag]

  const int t    = threadIdx.x;
  const int lane = t & 63;
  const int w    = t >> 6;
  const int h    = blockIdx.x & 1;
  const int n0   = (blockIdx.x >> 1) * 8 + w * 2;   // wave's first n
  const int colo = lane & 15;
  const int rgrp = lane >> 4;

  f32x4 acc[2][8] = {};                     // [np][og], unrolled-only indexing

  // lane = np*32 + c holds neighbor c of n0+np
  const int myidx = nbrs[(n0 + (lane >> 5)) * NK + (lane & 31)];

  const char* xb = (const char*)xb2h + ((size_t)(h * NN) << 11);
  const char* wf = (const char*)Wf2;

  auto loadA = [&](bf16x8 (*A)[2], int c) {   // 4 loads: 2 np x 2 ks
#pragma unroll
    for (int np = 0; np < 2; ++np) {
      const int nb = __builtin_amdgcn_readlane(myidx, np * 32 + c);
      const char* g = xb + ((size_t)nb << 11) + lane * 16;
      A[np][0] = *(const bf16x8*)(g);
      A[np][1] = *(const bf16x8*)(g + 1024);
    }
  };

  auto stageB = [&](int c) {                  // 16KB chunk (ksteps 2c,2c+1)
    const char* g = wf + ((size_t)c << 14) + (w << 12) + lane * 16;
    char* l = &lds[c & 1][w << 12];
#pragma unroll
    for (int q = 0; q < 4; ++q)
      __builtin_amdgcn_global_load_lds(
          (const GLOBAL_AS uint32_t*)(g + (q << 10)),
          (LDS_AS uint32_t*)(l + (q << 10)), 16, 0, 0);
  };

  auto compute = [&](int c, bf16x8 (*A)[2]) {
    const char* lb = &lds[c & 1][lane * 16];
    __builtin_amdgcn_s_setprio(1);
#pragma unroll
    for (int ks = 0; ks < 2; ++ks) {
#pragma unroll
      for (int og = 0; og < 8; ++og) {
        bf16x8 bf = *(const bf16x8*)(lb + (ks << 13) + (og << 10));
        acc[0][og] = MFMA16(A[0][ks], bf, acc[0][og], 0, 0, 0);
        acc[1][og] = MFMA16(A[1][ks], bf, acc[1][og], 0, 0, 0);
      }
    }
    __builtin_amdgcn_s_setprio(0);
  };

  bf16x8 A0[2][2], A1[2][2];

  // prologue: A(0), B(0)
  loadA(A0, 0); SB();
  stageB(0); SB();

#define BODY(C, AC, AL)                                     \
  loadA(AL, (C) + 1); SB();                                 \
  asm volatile("s_waitcnt vmcnt(4)" ::: "memory");          \
  __builtin_amdgcn_s_barrier(); SB();                       \
  compute((C), AC); SB();                                   \
  stageB((C) + 1); SB();

  // periods 0..29 (A-bank ping-pong), then 30, tail 31
  for (int c = 0; c < 30; c += 2) {
    BODY(c + 0, A0, A1)
    BODY(c + 1, A1, A0)
  }
  BODY(30, A0, A1)
#undef BODY
  // period 31: queue [A(31):4, B(31):4]
  asm volatile("s_waitcnt vmcnt(0)" ::: "memory");
  __builtin_amdgcn_s_barrier(); SB();
  compute(31, A1);

  // ---- distance kstep 64: A rows all equal d[n][k-slice]; B direct global
  {
    const char* wt = wf + ((size_t)64 << 13) + lane * 16;
    bf16x8 d0 = *(const bf16x8*)((const char*)db + (size_t)(n0 + 0) * 64 + (rgrp << 4));
    bf16x8 d1 = *(const bf16x8*)((const char*)db + (size_t)(n0 + 1) * 64 + (rgrp << 4));
#pragma unroll
    for (int og = 0; og < 8; ++og) {
      bf16x8 bf = *(const bf16x8*)(wt + (og << 10));
      acc[0][og] = MFMA16(d0, bf, acc[0][og], 0, 0, 0);
      acc[1][og] = MFMA16(d1, bf, acc[1][og], 0, 0, 0);
    }
  }

  // ---- epilogue: D col=lane&15 -> o=og*16+colo, row=(lane>>4)*4+r -> batch
#pragma unroll
  for (int og = 0; og < 8; ++og) {
    const int o = (og << 4) + colo;
    const float bv = bias[o];
#pragma unroll
    for (int r = 0; r < 4; ++r) {
      const int b = (h << 4) + (rgrp << 2) + r;
      float* op = out + ((size_t)b * NN + n0) * NOUT + o;
      op[0]    = acc[0][og][r] + bv;
      op[NOUT] = acc[1][og][r] + bv;
    }
  }
}

// ---------------------------------------------------------------------------
extern "C" void kernel_launch(void* const* d_in, const int* in_sizes, int n_in,
                              void* d_out, int out_size, void* d_ws, size_t ws_size,
                              hipStream_t stream) {
  const float* x    = (const float*)d_in[0];
  const int*   nbrs = (const int*)d_in[1];
  const float* dist = (const float*)d_in[2];
  const float* W    = (const float*)d_in[3];
  const float* bias = (const float*)d_in[4];
  float* out = (float*)d_out;

  char* ws = (char*)d_ws;
  __bf16* xb2h = (__bf16*)(ws);                          // 2*2000*2048 = 8,192,000 B
  __bf16* Wf2  = (__bf16*)(ws + 8192000);                // 65*8192     =   532,480 B
  __bf16* db   = (__bf16*)(ws + 8192000 + 532480);       // 2000*32*2   =   128,000 B

  kprep<<<NN + 65, 256, 0, stream>>>(x, dist, W, xb2h, db, Wf2);
  kmain<<<(NN / 8) * 2, 256, 0, stream>>>(nbrs, bias, xb2h, Wf2, db, out);
}

// Round 13
// 52.553 us; speedup vs baseline: 1.1195x; 1.0227x over previous
//
#include <hip/hip_runtime.h>
#include <hip/hip_bf16.h>
#include <stdint.h>

typedef __attribute__((ext_vector_type(8)))  __bf16   bf16x8;
typedef __attribute__((ext_vector_type(4)))  float    f32x4;
typedef __attribute__((ext_vector_type(8)))  float    f32x8;

#define NN   2000
#define NK   32
#define NOUT 128

#define GLOBAL_AS __attribute__((address_space(1)))
#define LDS_AS    __attribute__((address_space(3)))
#define SB() __builtin_amdgcn_sched_barrier(0)
#define MFMA16 __builtin_amdgcn_mfma_f32_16x16x32_bf16

// ---------------------------------------------------------------------------
// Prep (verified R12). Blocks [0,NN): x -> xb2h[h][n] 2KB half-tiles in
// 16x16x32 A-frag order + dist -> db bf16. Blocks [NN,NN+65): W -> Wf2
// B-frag order: byte = kstep*8192 + og*1024 + lane*16 + j*2 holds
// W[o=og*16+(l&15)][col(kg=kstep*32+(l>>4)*8+j)].
// ---------------------------------------------------------------------------
__global__ void kprep(const float* __restrict__ x, const float* __restrict__ dist,
                      const float* __restrict__ W,
                      __bf16* __restrict__ xb2h, __bf16* __restrict__ db,
                      __bf16* __restrict__ Wf2) {
  const int t = threadIdx.x;
  if (blockIdx.x < NN) {
    const int n = blockIdx.x;
    const int b  = t >> 3;          // batch 0..31
    const int f0 = (t & 7) << 3;    // feature start 0..56
    const float* src = x + ((size_t)b * NN + n) * 64 + f0;
    f32x8 v = *(const f32x8*)src;
    bf16x8 r;
#pragma unroll
    for (int j = 0; j < 8; ++j) r[j] = (__bf16)v[j];
    const int h = b >> 4, row = b & 15;
    const int off = ((f0 >> 5) << 10) + (((((f0 >> 3) & 3) << 4) + row) << 4);
    *(bf16x8*)((char*)xb2h + ((size_t)(h * NN + n) << 11) + off) = r;
    if (t < NK) db[n * NK + t] = (__bf16)dist[n * NK + t];
  } else {
    const int kstep = blockIdx.x - NN;      // 0..64
#pragma unroll
    for (int pass = 0; pass < 2; ++pass) {
      const int it = t + pass * 256;
      const int og = it >> 6, lane = it & 63;
      const int o  = og * 16 + (lane & 15);
      const int kb = kstep * 32 + ((lane >> 4) << 3);
      bf16x8 r;
#pragma unroll
      for (int j = 0; j < 8; ++j) {
        const int kg = kb + j;
        const int col = (kg < 2048) ? ((kg >> 6) * 65 + (kg & 63)) : ((kg - 2048) * 65 + 64);
        r[j] = (__bf16)W[(size_t)o * 2080 + col];
      }
      *(bf16x8*)((char*)Wf2 + (size_t)kstep * 8192 + og * 1024 + lane * 16) = r;
    }
  }
}

// ---------------------------------------------------------------------------
// Main: block = (half h, 8 n), 4 waves; wave = 2 n x ALL 128 out.
// Deep pipeline: A (random gather, global->reg) depth-3 periods in 4 named
// register banks; B (Wf2 stream, global_load_lds) depth-2 in 3 LDS bufs.
// Steady queue at each wait: [A(c):4,B(c):4,A(c+1):4,B(c+1):4,A(c+2):4]=20
// -> vmcnt(12) drains exactly A(c),B(c); 12 ops stay in flight ACROSS the
// barrier (the previous rounds drained to <=1 period -> sync killed depth).
// Body c: vmcnt(12) | barrier | stageB((c+2)%3, c+2) | loadA(bank(c+3)&3, c+3)
//         | compute(buf c%3, bank c&3).  Fully unrolled (29 bodies + tails).
// ---------------------------------------------------------------------------
__global__ __launch_bounds__(256, 2) void kmain(
    const int* __restrict__ nbrs, const float* __restrict__ bias,
    const __bf16* __restrict__ xb2h, const __bf16* __restrict__ Wf2,
    const __bf16* __restrict__ db, float* __restrict__ out) {
  __shared__ __align__(16) char lds[3][16384];   // [buf][2 kstep][8 og][1KB]

  const int t    = threadIdx.x;
  const int lane = t & 63;
  const int w    = t >> 6;
  const int h    = blockIdx.x & 1;
  const int n0   = (blockIdx.x >> 1) * 8 + w * 2;
  const int colo = lane & 15;
  const int rgrp = lane >> 4;

  f32x4 acc[2][8] = {};                     // [np][og], literal-indexed only

  const int myidx = nbrs[(n0 + (lane >> 5)) * NK + (lane & 31)];

  const char* xb = (const char*)xb2h + ((size_t)(h * NN) << 11);
  const char* wf = (const char*)Wf2;

  auto loadA = [&](bf16x8 (*A)[2], int c) {   // 4 loads: 2 np x 2 ks (4KB)
#pragma unroll
    for (int np = 0; np < 2; ++np) {
      const int nb = __builtin_amdgcn_readlane(myidx, np * 32 + c);
      const char* g = xb + ((size_t)nb << 11) + lane * 16;
      A[np][0] = *(const bf16x8*)(g);
      A[np][1] = *(const bf16x8*)(g + 1024);
    }
  };

  auto stageB = [&](int buf, int c) {         // 16KB chunk (ksteps 2c,2c+1)
    const char* g = wf + ((size_t)c << 14) + (w << 12) + lane * 16;
    char* l = &lds[buf][w << 12];
#pragma unroll
    for (int q = 0; q < 4; ++q)
      __builtin_amdgcn_global_load_lds(
          (const GLOBAL_AS uint32_t*)(g + (q << 10)),
          (LDS_AS uint32_t*)(l + (q << 10)), 16, 0, 0);
  };

  auto compute = [&](int buf, bf16x8 (*A)[2]) {
    const char* lb = &lds[buf][lane * 16];
    __builtin_amdgcn_s_setprio(1);
#pragma unroll
    for (int ks = 0; ks < 2; ++ks) {
#pragma unroll
      for (int og = 0; og < 8; ++og) {
        bf16x8 bf = *(const bf16x8*)(lb + (ks << 13) + (og << 10));
        acc[0][og] = MFMA16(A[0][ks], bf, acc[0][og], 0, 0, 0);
        acc[1][og] = MFMA16(A[1][ks], bf, acc[1][og], 0, 0, 0);
      }
    }
    __builtin_amdgcn_s_setprio(0);
  };

  bf16x8 A0[2][2], A1[2][2], A2[2][2], A3[2][2];   // 4 named banks (64 VGPR)

  // prologue: queue = [A(0),B(0),A(1),B(1),A(2)] = 20 ops
  loadA(A0, 0); SB();
  stageB(0, 0); SB();
  loadA(A1, 1); SB();
  stageB(1, 1); SB();
  loadA(A2, 2); SB();

#define BODY(C, ACUR, ALD, BUFC, BUFS)                      \
  asm volatile("s_waitcnt vmcnt(12)" ::: "memory");         \
  __builtin_amdgcn_s_barrier(); SB();                       \
  stageB(BUFS, (C) + 2); SB();                              \
  loadA(ALD, (C) + 3); SB();                                \
  compute(BUFC, ACUR); SB();

  // steady periods 0..28, fully unrolled (bank = C&3, buf = C%3, stage buf = (C+2)%3)
  BODY( 0, A0, A3, 0, 2)  BODY( 1, A1, A0, 1, 0)  BODY( 2, A2, A1, 2, 1)
  BODY( 3, A3, A2, 0, 2)  BODY( 4, A0, A3, 1, 0)  BODY( 5, A1, A0, 2, 1)
  BODY( 6, A2, A1, 0, 2)  BODY( 7, A3, A2, 1, 0)  BODY( 8, A0, A3, 2, 1)
  BODY( 9, A1, A0, 0, 2)  BODY(10, A2, A1, 1, 0)  BODY(11, A3, A2, 2, 1)
  BODY(12, A0, A3, 0, 2)  BODY(13, A1, A0, 1, 0)  BODY(14, A2, A1, 2, 1)
  BODY(15, A3, A2, 0, 2)  BODY(16, A0, A3, 1, 0)  BODY(17, A1, A0, 2, 1)
  BODY(18, A2, A1, 0, 2)  BODY(19, A3, A2, 1, 0)  BODY(20, A0, A3, 2, 1)
  BODY(21, A1, A0, 0, 2)  BODY(22, A2, A1, 1, 0)  BODY(23, A3, A2, 2, 1)
  BODY(24, A0, A3, 0, 2)  BODY(25, A1, A0, 1, 0)  BODY(26, A2, A1, 2, 1)
  BODY(27, A3, A2, 0, 2)  BODY(28, A0, A3, 1, 0)
#undef BODY

  // period 29: entry queue [A29,B29,A30,B30,A31]=20 -> vmcnt(12); stage B(31)
  asm volatile("s_waitcnt vmcnt(12)" ::: "memory");
  __builtin_amdgcn_s_barrier(); SB();
  stageB(1, 31); SB();
  compute(2, A1); SB();
  // period 30: queue [A30,B30,A31,B31]=16 -> vmcnt(8)
  asm volatile("s_waitcnt vmcnt(8)" ::: "memory");
  __builtin_amdgcn_s_barrier(); SB();
  compute(0, A2); SB();
  // period 31
  asm volatile("s_waitcnt vmcnt(0)" ::: "memory");
  __builtin_amdgcn_s_barrier(); SB();
  compute(1, A3);

  // ---- distance kstep 64: A rows all equal d[n][k-slice]; B direct global
  {
    const char* wt = wf + ((size_t)64 << 13) + lane * 16;
    bf16x8 d0 = *(const bf16x8*)((const char*)db + (size_t)(n0 + 0) * 64 + (rgrp << 4));
    bf16x8 d1 = *(const bf16x8*)((const char*)db + (size_t)(n0 + 1) * 64 + (rgrp << 4));
#pragma unroll
    for (int og = 0; og < 8; ++og) {
      bf16x8 bf = *(const bf16x8*)(wt + (og << 10));
      acc[0][og] = MFMA16(d0, bf, acc[0][og], 0, 0, 0);
      acc[1][og] = MFMA16(d1, bf, acc[1][og], 0, 0, 0);
    }
  }

  // ---- epilogue: D col=lane&15 -> o=og*16+colo, row=(lane>>4)*4+r -> batch
#pragma unroll
  for (int og = 0; og < 8; ++og) {
    const int o = (og << 4) + colo;
    const float bv = bias[o];
#pragma unroll
    for (int r = 0; r < 4; ++r) {
      const int b = (h << 4) + (rgrp << 2) + r;
      float* op = out + ((size_t)b * NN + n0) * NOUT + o;
      op[0]    = acc[0][og][r] + bv;
      op[NOUT] = acc[1][og][r] + bv;
    }
  }
}

// ---------------------------------------------------------------------------
extern "C" void kernel_launch(void* const* d_in, const int* in_sizes, int n_in,
                              void* d_out, int out_size, void* d_ws, size_t ws_size,
                              hipStream_t stream) {
  const float* x    = (const float*)d_in[0];
  const int*   nbrs = (const int*)d_in[1];
  const float* dist = (const float*)d_in[2];
  const float* W    = (const float*)d_in[3];
  const float* bias = (const float*)d_in[4];
  float* out = (float*)d_out;

  char* ws = (char*)d_ws;
  __bf16* xb2h = (__bf16*)(ws);                          // 2*2000*2048 = 8,192,000 B
  __bf16* Wf2  = (__bf16*)(ws + 8192000);                // 65*8192     =   532,480 B
  __bf16* db   = (__bf16*)(ws + 8192000 + 532480);       // 2000*32*2   =   128,000 B

  kprep<<<NN + 65, 256, 0, stream>>>(x, dist, W, xb2h, db, Wf2);
  kmain<<<(NN / 8) * 2, 256, 0, stream>>>(nbrs, bias, xb2h, Wf2, db, out);
}